// Round 6
// baseline (59.080 us; speedup 1.0000x reference)
//
#include <hip/hip_runtime.h>
#include <hip/hip_fp16.h>

#define CIN 32
#define COUT 64
#define NB 4
#define NPTS 32768
#define KNN 16

typedef unsigned short u16;
typedef unsigned char u8;
typedef float f2v __attribute__((ext_vector_type(2)));

__device__ __forceinline__ u16 f2h(float f) {
  _Float16 h = (_Float16)f;
  u16 u; __builtin_memcpy(&u, &h, 2); return u;
}
__device__ __forceinline__ f2v h2_to_f2(unsigned int u) {
  _Float16 a, b;
  __builtin_memcpy(&a, (const char*)&u, 2);
  __builtin_memcpy(&b, ((const char*)&u) + 2, 2);
  return (f2v){(float)a, (float)b};
}

// Kernel 1: local = W1@feat, edge = W2@feat, via v_pk_fma_f32 (float2 pairs
// over the CIN axis; weight pairs are consecutive in memory -> s_load pairs).
// Grid 2048x256; block = 64 n; 4 waves each own a uniform 32-row chunk of
// [W1;W2]. W1 waves apply BN+ReLU and write the k-independent central output
// half (fp32, coalesced) + raw local as fp16 (B,N,64). W2 waves write the
// edge table as fp8 e4m3 (B,N,64) -> 2 MiB/batch, L2/L3-resident for k2.
__global__ __launch_bounds__(256) void k1_gemm(
    const float* __restrict__ feat, const float* __restrict__ W1,
    const float* __restrict__ W2, const float* __restrict__ gamma,
    const float* __restrict__ beta, const float* __restrict__ mean,
    const float* __restrict__ var, u16* __restrict__ lt, u8* __restrict__ et,
    float* __restrict__ out) {
  const int bid = blockIdx.x;
  const int b = bid >> 9;
  const int n0 = (bid & 511) << 6;
  const int t = threadIdx.x;
  const int lane = t & 63;
  const int wchunk = __builtin_amdgcn_readfirstlane(t >> 6);
  const int n = n0 + lane;

  f2v fv[16];
  const float* fp = feat + (size_t)b * CIN * NPTS + n;
#pragma unroll
  for (int c2 = 0; c2 < 16; ++c2)
    fv[c2] = (f2v){fp[(size_t)(2 * c2) * NPTS], fp[(size_t)(2 * c2 + 1) * NPTS]};

  const int half = wchunk >> 1;        // 0 -> W1 (local), 1 -> W2 (edge fp8)
  const int rbase = (wchunk & 1) * 32;
  const float* Wp = half ? W2 : W1;

  unsigned int pkh[16];  // fp16 pack (local waves)
  unsigned int pk8[8];   // fp8 pack (edge waves)

#pragma unroll
  for (int oo = 0; oo < 32; oo += 4) {
    const float* w0 = Wp + (size_t)(rbase + oo) * CIN;
    const f2v* wr0 = reinterpret_cast<const f2v*>(w0);
    const f2v* wr1 = reinterpret_cast<const f2v*>(w0 + CIN);
    const f2v* wr2 = reinterpret_cast<const f2v*>(w0 + 2 * CIN);
    const f2v* wr3 = reinterpret_cast<const f2v*>(w0 + 3 * CIN);
    f2v p0 = (f2v)0.f, p1 = (f2v)0.f, p2 = (f2v)0.f, p3 = (f2v)0.f;
#pragma unroll
    for (int c2 = 0; c2 < 16; ++c2) {
      const f2v fc = fv[c2];
      p0 = __builtin_elementwise_fma(wr0[c2], fc, p0);
      p1 = __builtin_elementwise_fma(wr1[c2], fc, p1);
      p2 = __builtin_elementwise_fma(wr2[c2], fc, p2);
      p3 = __builtin_elementwise_fma(wr3[c2], fc, p3);
    }
    const float a0 = p0.x + p0.y, a1 = p1.x + p1.y;
    const float a2 = p2.x + p2.y, a3 = p3.x + p3.y;
    if (half == 0) {
      pkh[oo / 2]     = (unsigned)f2h(a0) | ((unsigned)f2h(a1) << 16);
      pkh[oo / 2 + 1] = (unsigned)f2h(a2) | ((unsigned)f2h(a3) << 16);
      const float acc[4] = {a0, a1, a2, a3};
#pragma unroll
      for (int i = 0; i < 4; ++i) {
        const int r = rbase + oo + i;
        const float iv = gamma[r] * rsqrtf(var[r] + 1e-5f);
        const float sh = beta[r] - mean[r] * iv;
        out[((size_t)b * 128 + r) * NPTS + n] = fmaxf(fmaf(acc[i], iv, sh), 0.f);
      }
    } else {
      int u = 0;
      u = __builtin_amdgcn_cvt_pk_fp8_f32(a0, a1, u, false);
      u = __builtin_amdgcn_cvt_pk_fp8_f32(a2, a3, u, true);
      pk8[oo / 4] = (unsigned)u;
    }
  }
  if (half == 0) {
    uint4* dp = reinterpret_cast<uint4*>(lt + ((size_t)(b * NPTS + n)) * COUT + rbase);
#pragma unroll
    for (int q = 0; q < 4; ++q)
      dp[q] = make_uint4(pkh[4 * q], pkh[4 * q + 1], pkh[4 * q + 2], pkh[4 * q + 3]);
  } else {
    uint4* dp = reinterpret_cast<uint4*>(et + ((size_t)(b * NPTS + n)) * COUT + rbase);
    dp[0] = make_uint4(pk8[0], pk8[1], pk8[2], pk8[3]);
    dp[1] = make_uint4(pk8[4], pk8[5], pk8[6], pk8[7]);
  }
}

// Kernel 2: diff half. lane = nn*4+cq: thread owns (n = n_blk + w*16 + nn,
// channels 16cq..16cq+15). 16 gathers of 16B (uint4); 4 lanes cover one 64B
// fp8 row = 1 cache line, so each gather wave-inst pulls 16 lines (vs 8 at
// 8B/lane) -> half the gather instruction count. All K in-lane, no shuffles.
// Decode via v_cvt_pk_f32_fp8, v_pk_fma/max/add_f32. XCD-swizzled grid.
// Output staged in LDS (pad 65 -> 2-way only), written as coalesced float4.
__global__ __launch_bounds__(256) void k2_gather(
    const u16* __restrict__ lt, const u8* __restrict__ et,
    const int* __restrict__ knn, const float* __restrict__ gamma,
    const float* __restrict__ beta, const float* __restrict__ mean,
    const float* __restrict__ var, float* __restrict__ out) {
  __shared__ float obuf[64 * 65];
  int bid = blockIdx.x;
  bid = (bid & 7) * 256 + (bid >> 3);   // 2048 % 8 == 0 -> bijective
  const int b = bid >> 9;               // 512 blocks per batch
  const int n_blk = (bid & 511) << 6;   // 64 n per block
  const int t = threadIdx.x;
  const int w = t >> 6;
  const int lane = t & 63;
  const int nn = lane >> 2;   // 0..15
  const int cq = lane & 3;    // 0..3
  const int ch = cq * 16;     // 16 channels per lane

  const int n = n_blk + w * 16 + nn;
  const size_t rowbase = (size_t)b * NPTS;

  // knn row: 16 idx = 4x int4 (broadcast across the 4 cq lanes)
  const int4* kp = reinterpret_cast<const int4*>(knn + (rowbase + n) * KNN);
  const int4 kv0 = kp[0], kv1 = kp[1], kv2 = kp[2], kv3 = kp[3];
  // local row: 16 fp16 = 32B
  const uint4* lp = reinterpret_cast<const uint4*>(lt + (rowbase + n) * COUT + ch);
  const uint4 lv0 = lp[0], lv1 = lp[1];

  // issue all 16 gathers (16B fp8 each = 16 channels)
  const u8* etb = et + rowbase * COUT + ch;
  const int idx[16] = {kv0.x, kv0.y, kv0.z, kv0.w, kv1.x, kv1.y, kv1.z, kv1.w,
                       kv2.x, kv2.y, kv2.z, kv2.w, kv3.x, kv3.y, kv3.z, kv3.w};
  uint4 e[16];
#pragma unroll
  for (int k = 0; k < 16; ++k)
    e[k] = *reinterpret_cast<const uint4*>(etb + ((size_t)idx[k] << 6));

  // BN constants + tt_i = sh_i - local_i * inv_i for 16 channels (8 f2v)
  f2v inv[8], tt[8];
  const unsigned int lw[8] = {lv0.x, lv0.y, lv0.z, lv0.w, lv1.x, lv1.y, lv1.z, lv1.w};
#pragma unroll
  for (int i = 0; i < 8; ++i) {
    const int r0 = 64 + ch + 2 * i;
    const float iv0 = gamma[r0] * rsqrtf(var[r0] + 1e-5f);
    const float iv1 = gamma[r0 + 1] * rsqrtf(var[r0 + 1] + 1e-5f);
    inv[i] = (f2v){iv0, iv1};
    const f2v sh = (f2v){beta[r0] - mean[r0] * iv0, beta[r0 + 1] - mean[r0 + 1] * iv1};
    tt[i] = sh - h2_to_f2(lw[i]) * inv[i];
  }

  f2v acc[8] = {(f2v)0.f, (f2v)0.f, (f2v)0.f, (f2v)0.f,
                (f2v)0.f, (f2v)0.f, (f2v)0.f, (f2v)0.f};
  const f2v zero = (f2v)0.f;
#pragma unroll
  for (int k = 0; k < 16; ++k) {
    const unsigned int ew[4] = {e[k].x, e[k].y, e[k].z, e[k].w};
#pragma unroll
    for (int q = 0; q < 4; ++q) {
      const f2v dlo = __builtin_amdgcn_cvt_pk_f32_fp8(ew[q], false);
      const f2v dhi = __builtin_amdgcn_cvt_pk_f32_fp8(ew[q], true);
      acc[2 * q] += __builtin_elementwise_max(
          __builtin_elementwise_fma(dlo, inv[2 * q], tt[2 * q]), zero);
      acc[2 * q + 1] += __builtin_elementwise_max(
          __builtin_elementwise_fma(dhi, inv[2 * q + 1], tt[2 * q + 1]), zero);
    }
  }

  const int nc = w * 16 + nn;
#pragma unroll
  for (int i = 0; i < 8; ++i) {
    obuf[(ch + 2 * i) * 65 + nc] = acc[i].x * 0.0625f;
    obuf[(ch + 2 * i + 1) * 65 + nc] = acc[i].y * 0.0625f;
  }
  __syncthreads();
#pragma unroll
  for (int r = 0; r < 4; ++r) {
    const int c = r * 16 + (t >> 4);
    const int q4 = (t & 15) * 4;
    float4 v = make_float4(obuf[c * 65 + q4], obuf[c * 65 + q4 + 1],
                           obuf[c * 65 + q4 + 2], obuf[c * 65 + q4 + 3]);
    *reinterpret_cast<float4*>(out + ((size_t)b * 128 + 64 + c) * NPTS + n_blk + q4) = v;
  }
}

extern "C" void kernel_launch(void* const* d_in, const int* in_sizes, int n_in,
                              void* d_out, int out_size, void* d_ws, size_t ws_size,
                              hipStream_t stream) {
  const float* feat  = (const float*)d_in[0];
  const int*   knn   = (const int*)d_in[1];
  const float* W1    = (const float*)d_in[2];
  const float* W2    = (const float*)d_in[3];
  const float* gamma = (const float*)d_in[4];
  const float* beta  = (const float*)d_in[5];
  const float* mean  = (const float*)d_in[6];
  const float* var   = (const float*)d_in[7];
  float* out = (float*)d_out;

  u16* lt = (u16*)d_ws;                           // (B,N,64) fp16 local, 16.8 MB
  u8* et = (u8*)(lt + (size_t)NB * NPTS * COUT);  // (B,N,64) fp8 edge, 8.4 MB

  k1_gemm<<<dim3(NB * NPTS / 64), 256, 0, stream>>>(feat, W1, W2, gamma, beta,
                                                    mean, var, lt, et, out);
  k2_gather<<<dim3(NB * NPTS / 64), 256, 0, stream>>>(lt, et, knn, gamma, beta,
                                                      mean, var, out);
}